// Round 11
// baseline (121.129 us; speedup 1.0000x reference)
//
#include <hip/hip_runtime.h>

#define DEVI __device__ __forceinline__

constexpr int N_ = 2, C_ = 80, H_ = 32, W_ = 40, HW_ = H_ * W_, HWC_ = HW_ * C_;
constexpr int KTOP = 1000, M2_ = 196;
constexpr int IMH = 256, IMW = 320;
constexpr int NB = 2048;          // f32-derived bins
constexpr int KB = 16;            // hist slices per image
constexpr int SLICE = HWC_ / KB;  // 6400 = 5*HW_
constexpr int BCAP = 2048;        // rank working-set cap (expected G ~ 1100)
constexpr int GCAP = 4096;        // global buf cap

// output layout (floats): bx[2][100][4] | sc[2][100] | lb[2][100] | prob[2][100][196] | vf[2][100]
constexpr int O_SC = 800, O_LB = 1000, O_PB = 1200, O_VF = 40400;

DEVI unsigned long long mapd(double v) {
  unsigned long long u = (unsigned long long)__double_as_longlong(v);
  return (u & 0x8000000000000000ull) ? ~u : (u | 0x8000000000000000ull);
}
DEVI double unmapd(unsigned long long k) {
  unsigned long long u = (k & 0x8000000000000000ull) ? (k ^ 0x8000000000000000ull) : ~k;
  return __longlong_as_double((long long)u);
}
DEVI int i0of(int x, int cap) {  // exact first contributing mask row/col (matches table arithmetic)
  float src = ((float)x + 0.5f) * 0.125f - 0.5f;
  src = fminf(fmaxf(src, 0.f), (float)cap);
  return (int)floorf(src);
}

// ---- K1: per-slice f32 hist | mask transpose/sigmoid | weight tables (verbatim r10) ----
__global__ __launch_bounds__(1024) void k_pre(const float* cls, const float* cent, const float* bm,
                                              unsigned* ghist, float* msig, float* wr, float* wc) {
  int b = blockIdx.x, tid = threadIdx.x;
  if (b < N_ * KB) {
    __shared__ unsigned hist[NB];
    __shared__ float ce[HW_];
    int n = b >> 4, sb = b & 15;
    size_t base = (size_t)n * HWC_ + (size_t)sb * SLICE;
    for (int j = tid; j < NB; j += 1024) hist[j] = 0;
    for (int j = tid; j < HW_; j += 1024) ce[j] = 1.f / (1.f + expf(-cent[n * HW_ + j]));
    __syncthreads();
    #pragma unroll
    for (int it = 0; it < 7; ++it) {
      int j = it * 1024 + tid;
      if (j < SLICE) {
        float aa = cls[base + j];
        float s = 1.f / (1.f + expf(-aa));
        // conservative band: f32 s <= 0.0499999 implies exact sigmoid < 0.05 (exclude safely);
        // borderline entries get the exact f64 gate downstream. (r6-r10-proven scheme)
        if (s > 0.0499999f) {
          unsigned key = __float_as_uint(s * ce[j % HW_]);   // base is a multiple of HW_
          int bin = (int)(key >> 16) - 0x3800;
          bin = bin < 0 ? 0 : (bin > NB - 1 ? NB - 1 : bin);
          atomicAdd(&hist[bin], 1u);
        }
      }
    }
    __syncthreads();
    unsigned* gh = ghist + ((size_t)n * KB + sb) * NB;
    for (int j = tid; j < NB; j += 1024) gh[j] = hist[j];
  } else if (b < N_ * KB + 140) {
    __shared__ float tile[4][32][33];
    int g = tid >> 8, sub = tid & 255;
    int tt = (b - N_ * KB) * 4 + g;             // 0..559
    int n = tt / 280, r = tt % 280, rqt = r / 7, ct = r % 7;
    int tx = sub & 31, ty = sub >> 5;           // 32x8
    int rq0 = rqt * 32, c0 = ct * 32;
    for (int i = 0; i < 4; ++i) {
      int cc = c0 + ty + i * 8, rq = rq0 + tx;
      if (cc < M2_) {
        float v = bm[((size_t)n * M2_ + cc) * HW_ + rq];
        tile[g][ty + i * 8][tx] = 1.f / (1.f + expf(-v));
      }
    }
    __syncthreads();
    for (int i = 0; i < 4; ++i) {
      int rq = rq0 + ty + i * 8, cc = c0 + tx;
      if (cc < M2_) msig[((size_t)n * HW_ + rq) * M2_ + cc] = tile[g][tx][ty + i * 8];
    }
  } else {
    int t = tid;
    if (t < H_) {
      int r = t; float acc = 0.f; wr[0 * H_ + r] = 0.f;
      for (int x = 0; x < IMH; ++x) {
        float src = ((float)x + 0.5f) * ((float)H_ / (float)IMH) - 0.5f;
        src = fminf(fmaxf(src, 0.f), (float)(H_ - 1));
        int i0 = (int)floorf(src); int i1 = min(i0 + 1, H_ - 1);
        float lam = src - (float)i0;
        float w = ((r == i0) ? (1.f - lam) : 0.f) + ((r == i1) ? lam : 0.f);
        acc += w; wr[(x + 1) * H_ + r] = acc;
      }
    } else if (t < H_ + W_) {
      int q = t - H_; float acc = 0.f; wc[0 * W_ + q] = 0.f;
      for (int y = 0; y < IMW; ++y) {
        float src = ((float)y + 0.5f) * ((float)W_ / (float)IMW) - 0.5f;
        src = fminf(fmaxf(src, 0.f), (float)(W_ - 1));
        int i0 = (int)floorf(src); int i1 = min(i0 + 1, W_ - 1);
        float lam = src - (float)i0;
        float w = ((q == i0) ? (1.f - lam) : 0.f) + ((q == i1) ? lam : 0.f);
        acc += w; wc[(y + 1) * W_ + q] = acc;
      }
    }
  }
}

// ---- K2: 32 blocks: redundant D,Dg -> slice compact (exact-f32 bin predicate, consistent
//          with hist offsets) -> write EXACT f64 keys + idx; zero keepg (r5-proven skeleton) ----
__global__ __launch_bounds__(1024) void k_compact(const unsigned* ghist, const float* cls, const float* cent,
                                                  unsigned long long* bufK, unsigned* bufI, unsigned* cntG,
                                                  unsigned* keepg) {
  __shared__ unsigned wtot[16], wabove[16], sliceCnt[16], sliceOff[17];
  __shared__ unsigned sD, lcnt;
  __shared__ float ce[HW_];
  int b = blockIdx.x, n = b >> 4, sb = b & 15;
  int tid = threadIdx.x, lane = tid & 63, wid = tid >> 6;
  if (tid < 64) keepg[b * 64 + tid] = 0;
  for (int j = tid; j < HW_; j += 1024) ce[j] = 1.f / (1.f + expf(-cent[n * HW_ + j]));
  const unsigned* gh = ghist + (size_t)n * KB * NB;
  unsigned a = 0, bv = 0;
  #pragma unroll
  for (int q = 0; q < KB; ++q) { a += gh[q * NB + 2 * tid]; bv += gh[q * NB + 2 * tid + 1]; }
  if (tid == 0) { sD = 0; lcnt = 0; }
  unsigned s2 = a + bv, suf = s2;
  for (int off = 1; off < 64; off <<= 1) {
    unsigned v = __shfl_down(suf, off);
    if (lane + off < 64) suf += v;
  }
  if (lane == 0) wtot[wid] = suf;
  __syncthreads();
  if (tid == 0) { unsigned acc = 0; for (int w = 15; w >= 0; --w) { wabove[w] = acc; acc += wtot[w]; } }
  __syncthreads();
  unsigned above = (suf - s2) + wabove[wid];
  if (above < 1000u && above + bv >= 1000u) sD = (unsigned)(2 * tid + 1);
  if (above + bv < 1000u && above + bv + a >= 1000u) sD = (unsigned)(2 * tid);
  __syncthreads();
  unsigned D = sD;
  unsigned Dg = (D > 0) ? D - 1 : 0;            // guard bin covers f32-vs-f64 straddle (r6-proven)
  // per-slice counts of bins >= Dg (wave w owns slice w) -> deterministic offsets
  {
    unsigned acc = 0;
    for (int bin = (int)Dg + lane; bin < NB; bin += 64) acc += gh[wid * NB + bin];
    for (int off = 32; off; off >>= 1) acc += __shfl_down(acc, off);
    if (lane == 0) sliceCnt[wid] = acc;
  }
  __syncthreads();
  if (tid == 0) {
    unsigned acc = 0;
    for (int q = 0; q < KB; ++q) { sliceOff[q] = acc; acc += sliceCnt[q]; }
    sliceOff[KB] = acc;
    if (sb == 0) cntG[n] = acc;
  }
  __syncthreads();
  unsigned myStart = sliceOff[sb];
  size_t gbase = (size_t)n * HWC_ + (size_t)sb * SLICE;
  for (int it = 0; it < 7; ++it) {
    int j = it * 1024 + tid;
    bool win = false; float aa = 0.f;
    if (j < SLICE) {
      aa = cls[gbase + j];
      float s = 1.f / (1.f + expf(-aa));
      if (s > 0.0499999f) {
        unsigned key = __float_as_uint(s * ce[j % HW_]);
        int bin = (int)(key >> 16) - 0x3800;
        bin = bin < 0 ? 0 : (bin > NB - 1 ? NB - 1 : bin);
        win = ((unsigned)bin >= Dg);
      }
    }
    unsigned long long mb = __ballot(win);
    if (mb) {
      int lead = __builtin_ctzll(mb);
      unsigned offw = 0;
      if (lane == lead) offw = atomicAdd(&lcnt, (unsigned)__popcll(mb));
      offw = (unsigned)__shfl((int)offw, lead);
      if (win) {
        unsigned pos = myStart + offw + (unsigned)__popcll(mb & ((1ull << lane) - 1ull));
        if (pos < (unsigned)GCAP) {
          int hw = j % HW_, c = sb * 5 + j / HW_;   // SLICE = 5*HW_
          double ss = 1.0 / (1.0 + exp(-(double)aa));
          double ced = 1.0 / (1.0 + exp(-(double)cent[n * HW_ + hw]));
          double v = (ss > 0.05) ? ss * ced : -1e9; // exact reference gate + key
          bufK[(size_t)n * GCAP + pos] = mapd(v);
          bufI[(size_t)n * GCAP + pos] = (unsigned)(hw * C_ + c);  // logical [HW,C] flat index
        }
      }
    }
  }
}

// ---- shared rank machinery: exact counting sort by f32-cast bucket + within-bucket rank
//      (r10-proven; pure function of (bufK,bufI,G) => identical in every block) ----
struct RankA {
  unsigned long long K[BCAP];
  unsigned I[BCAP];
  unsigned short eb[BCAP];
  unsigned short ord[BCAP];
  unsigned bh[NB], bs[NB], cur[NB];
};

DEVI void rank_sort_256(RankA& A, unsigned long long* Ks, unsigned* Is,
                        unsigned* wtot, unsigned* wabove,
                        const unsigned long long* bufK, const unsigned* bufI, int G,
                        int tid, int lane, int wid) {
  for (int p = tid; p < G; p += 256) { A.K[p] = bufK[p]; A.I[p] = bufI[p]; }
  for (int j = tid; j < NB; j += 256) A.bh[j] = 0;
  __syncthreads();
  for (int p = tid; p < G; p += 256) {
    double v = unmapd(A.K[p]);
    int bb = 0;
    if (v > 0.0) {                              // f64->f32 cast monotone => bucket order exact
      unsigned kb = __float_as_uint((float)v);
      bb = (int)(kb >> 16) - 0x3800;
      bb = bb < 0 ? 0 : (bb > NB - 1 ? NB - 1 : bb);
    }
    A.eb[p] = (unsigned short)bb;
    atomicAdd(&A.bh[bb], 1u);
  }
  __syncthreads();
  unsigned loc[8]; unsigned s = 0;
  int b0 = tid * 8;                             // thread owns bins [8t, 8t+8)
  #pragma unroll
  for (int j = 0; j < 8; ++j) { loc[j] = A.bh[b0 + j]; s += loc[j]; }
  unsigned suf = s;
  for (int off = 1; off < 64; off <<= 1) {
    unsigned v = __shfl_down(suf, off);
    if (lane + off < 64) suf += v;
  }
  if (lane == 0) wtot[wid] = suf;
  __syncthreads();
  if (tid == 0) { unsigned acc = 0; for (int w = 3; w >= 0; --w) { wabove[w] = acc; acc += wtot[w]; } }
  __syncthreads();
  unsigned run = (suf - s) + wabove[wid];       // count in bins above this thread's range
  for (int j = 7; j >= 0; --j) { A.bs[b0 + j] = run; A.cur[b0 + j] = run; run += loc[j]; }
  __syncthreads();
  for (int p = tid; p < G; p += 256) { unsigned p2 = atomicAdd(&A.cur[A.eb[p]], 1u); A.ord[p2] = (unsigned short)p; }
  __syncthreads();
  for (int p = tid; p < G; p += 256) {
    int bb = A.eb[p];
    unsigned lo = A.bs[bb], len = A.bh[bb];
    unsigned long long k1 = A.K[p]; unsigned i1 = A.I[p];
    unsigned r = lo;
    for (unsigned q = lo; q < lo + len; ++q) {
      int j = A.ord[q];
      unsigned long long kj = A.K[j]; unsigned ij = A.I[j];
      if ((kj > k1) || (kj == k1 && ij < i1)) ++r;   // strict total order => permutation
    }
    if (r < 1024u) { Ks[r] = k1; Is[r] = i1; }
  }
  for (int j = G + tid; j < 1024; j += 256) { Ks[j] = 0ull; Is[j] = 0xFFFFFFFFu; }
  __syncthreads();
}

struct NmsB {
  double mb0[1024], mb1[1024], mb2[1024], mb3[1024], ma[1024];
  double bx[128][5];
  unsigned short ml[128];
  unsigned char labA[1024], vldA[1024];
};
union NmsU { RankA a; NmsB b; };

// ---- K3: per-(image,class): redundant rank+decode -> single-wave register-mask NMS (r7-proven) ----
__global__ __launch_bounds__(256) void k_nms(const unsigned long long* bufK, const unsigned* bufI,
                                             const unsigned* cntG, const float* loc, const float* breg,
                                             unsigned* keepg) {
  __shared__ NmsU u;
  __shared__ unsigned long long Ks[1024];
  __shared__ unsigned Is[1024];
  __shared__ unsigned wtot[4], wabove[4];
  int cls_ = blockIdx.x + 1, n = blockIdx.y;
  int tid = threadIdx.x, lane = tid & 63, wid = tid >> 6;
  int G = (int)cntG[n]; if (G > BCAP) G = BCAP;
  rank_sort_256(u.a, Ks, Is, wtot, wabove,
                bufK + (size_t)n * GCAP, bufI + (size_t)n * GCAP, G, tid, lane, wid);
  // decode clipped boxes/labels/valid into u.b (rank structs dead; union switch after barrier)
  for (int p = tid; p < 1024; p += 256) {
    unsigned long long key = Ks[p]; unsigned idx = Is[p];
    double v = unmapd(key);
    int valid = (v > -5e8) && (idx < (unsigned)HWC_);
    if (idx >= (unsigned)HWC_) idx = 0;
    int hw = (int)(idx / C_), c = (int)(idx % C_);
    double lx = (double)loc[hw * 2 + 0], ly = (double)loc[hw * 2 + 1];
    const float* rg4 = breg + (size_t)n * 4 * HW_;
    double r0 = (double)rg4[0 * HW_ + hw], r1 = (double)rg4[1 * HW_ + hw];
    double r2 = (double)rg4[2 * HW_ + hw], r3 = (double)rg4[3 * HW_ + hw];
    double b0 = lx - r0, b1 = ly - r1, b2 = lx + r2, b3 = ly + r3;
    double c0 = fmin(fmax(b0, 0.0), (double)(IMW - 1));
    double c1 = fmin(fmax(b1, 0.0), (double)(IMH - 1));
    double c2 = fmin(fmax(b2, 0.0), (double)(IMW - 1));
    double c3 = fmin(fmax(b3, 0.0), (double)(IMH - 1));
    u.b.mb0[p] = c0; u.b.mb1[p] = c1; u.b.mb2[p] = c2; u.b.mb3[p] = c3;
    u.b.ma[p] = (c2 - c0 + 1.0) * (c3 - c1 + 1.0);
    u.b.labA[p] = (unsigned char)(c + 1);
    u.b.vldA[p] = (unsigned char)((valid != 0) && (p < KTOP));
  }
  __syncthreads();
  if (tid < 64) {                               // single wave; no block barriers (r7-proven)
    int m = 0;
    for (int ch = 0; ch < 16; ++ch) {
      int e = ch * 64 + lane;
      bool pred = (e < KTOP) && u.b.vldA[e] && ((int)u.b.labA[e] == cls_);
      unsigned long long bb = __ballot(pred);
      if (pred) {
        int pos = m + (int)__popcll(bb & ((1ull << lane) - 1ull));
        if (pos < 128) {
          u.b.bx[pos][0] = u.b.mb0[e]; u.b.bx[pos][1] = u.b.mb1[e];
          u.b.bx[pos][2] = u.b.mb2[e]; u.b.bx[pos][3] = u.b.mb3[e];
          u.b.bx[pos][4] = u.b.ma[e];
          u.b.ml[pos] = (unsigned short)e;
        }
      }
      m += (int)__popcll(bb);
    }
    if (m > 128) m = 128;
    __builtin_amdgcn_wave_barrier();
    unsigned long long k0 = (m >= 64) ? ~0ull : ((1ull << m) - 1ull);
    unsigned long long k1m = (m > 64) ? ((m >= 128) ? ~0ull : ((1ull << (m - 64)) - 1ull)) : 0ull;
    for (int i = 0; i < m; ++i) {
      bool alive = (i < 64) ? ((k0 >> i) & 1ull) : ((k1m >> (i - 64)) & 1ull);
      if (!alive) continue;                     // uniform across lanes
      double x1 = u.b.bx[i][0], y1 = u.b.bx[i][1], x2 = u.b.bx[i][2], y2 = u.b.bx[i][3], ai = u.b.bx[i][4];
      {
        int j = lane;
        bool ok = (j < m) && (j > i);
        int jj = ok ? j : 0;
        double u1 = u.b.bx[jj][0], v1 = u.b.bx[jj][1], u2 = u.b.bx[jj][2], v2 = u.b.bx[jj][3], aj = u.b.bx[jj][4];
        double ltx = fmax(x1, u1), lty = fmax(y1, v1), rbx = fmin(x2, u2), rby = fmin(y2, v2);
        double iw = fmax(rbx - ltx + 1.0, 0.0), ih = fmax(rby - lty + 1.0, 0.0);
        double inter = iw * ih, uni = ai + aj - inter;
        bool sup = ok && (inter / fmax(uni, 1e-6) > 0.6);
        k0 &= ~__ballot(sup);
      }
      if (m > 64) {
        int j = 64 + lane;
        bool ok = (j < m) && (j > i);
        int jj = ok ? j : 0;
        double u1 = u.b.bx[jj][0], v1 = u.b.bx[jj][1], u2 = u.b.bx[jj][2], v2 = u.b.bx[jj][3], aj = u.b.bx[jj][4];
        double ltx = fmax(x1, u1), lty = fmax(y1, v1), rbx = fmin(x2, u2), rby = fmin(y2, v2);
        double iw = fmax(rbx - ltx + 1.0, 0.0), ih = fmax(rby - lty + 1.0, 0.0);
        double inter = iw * ih, uni = ai + aj - inter;
        bool sup = ok && (inter / fmax(uni, 1e-6) > 0.6);
        k1m &= ~__ballot(sup);
      }
    }
    for (int j = lane; j < m; j += 64) {
      bool kb2 = (j < 64) ? ((k0 >> j) & 1ull) : ((k1m >> (j - 64)) & 1ull);
      keepg[n * 1024 + u.b.ml[j]] = kb2 ? 1u : 0u;
    }
  }
}

// ---- K4: redundant rank -> stable partition (keepg) -> decode ONE candidate -> outputs + prob ----
__global__ __launch_bounds__(256) void k_finish(const unsigned long long* bufK, const unsigned* bufI,
                                                const unsigned* cntG, const float* loc, const float* breg,
                                                const unsigned* keepg, const float* msig,
                                                const float* wr, const float* wc, float* out) {
  __shared__ RankA ra;
  __shared__ unsigned long long Ks[1024];
  __shared__ unsigned Is[1024];
  __shared__ unsigned wtot[4], wabove[4];
  __shared__ int lsel[100], lvf[100];
  __shared__ unsigned woff[4]; __shared__ unsigned sS;
  __shared__ float Aw[H_], Bw[W_];
  int t = blockIdx.x, n = blockIdx.y;
  int tid = threadIdx.x, lane = tid & 63, wid = tid >> 6;
  int G = (int)cntG[n]; if (G > BCAP) G = BCAP;
  rank_sort_256(ra, Ks, Is, wtot, wabove,
                bufK + (size_t)n * GCAP, bufI + (size_t)n * GCAP, G, tid, lane, wid);

  // stable partition by keep flag (r5-proven; thread owns entries [4tid,4tid+4))
  int i0 = tid * 4;
  unsigned ff[4]; int lc = 0;
  for (int j = 0; j < 4; ++j) {
    int i = i0 + j;
    ff[j] = (i < KTOP) ? keepg[n * 1024 + i] : 0u;
    lc += (int)ff[j];
  }
  unsigned pre = (unsigned)lc;
  for (int off = 1; off < 64; off <<= 1) {
    unsigned v = __shfl_up(pre, off);
    if (lane >= off) pre += v;
  }
  if (lane == 63) woff[wid] = pre;
  __syncthreads();
  if (tid == 0) { unsigned acc = 0; for (int w = 0; w < 4; ++w) { unsigned tmp = woff[w]; woff[w] = acc; acc += tmp; } sS = acc; }
  __syncthreads();
  int kpre = (int)(woff[wid] + pre - (unsigned)lc);
  int S = (int)sS;
  for (int j = 0; j < 4; ++j) {
    int i = i0 + j;
    if (i < KTOP) {
      if (ff[j]) { if (kpre < 100) { lsel[kpre] = i; lvf[kpre] = 1; } kpre++; }
      else { int slot = S + (i - kpre); if (slot < 100) { lsel[slot] = i; lvf[slot] = 0; } }
    }
  }
  __syncthreads();

  int k = lsel[t], vf = lvf[t];
  // decode the selected candidate (all threads redundantly; verbatim r5 math)
  unsigned long long key = Ks[k]; unsigned idx = Is[k];
  double v = unmapd(key);
  int valid = (v > -5e8) && (idx < (unsigned)HWC_);
  if (idx >= (unsigned)HWC_) idx = 0;
  int hw = (int)(idx / C_), c = (int)(idx % C_);
  double lx = (double)loc[hw * 2 + 0], ly = (double)loc[hw * 2 + 1];
  const float* rg4 = breg + (size_t)n * 4 * HW_;
  double r0 = (double)rg4[0 * HW_ + hw], r1 = (double)rg4[1 * HW_ + hw];
  double r2 = (double)rg4[2 * HW_ + hw], r3 = (double)rg4[3 * HW_ + hw];
  double b0 = lx - r0, b1 = ly - r1, b2 = lx + r2, b3 = ly + r3;
  double sc = valid ? sqrt(v) : 0.0;
  int bi0 = (int)b0, bi1 = (int)b1, bi2 = (int)b2, bi3 = (int)b3;
  int x1 = max(bi0, 0), x2 = min(bi2, IMH - 1), y1 = max(bi1, 0), y2 = min(bi3, IMW - 1);
  int rok = (x1 < x2) && (y1 < x2) && (y1 < y2);   // ref bug replicated
  int x1c = min(max(x1, 0), IMH), x2c = min(max(x2, 0), IMH);
  int y1c = min(max(y1, 0), IMW), y2c = min(max(y2, 0), IMW);
  int area = max((x2c - x1c) * (y2c - y1c), 1);
  double c0 = fmin(fmax(b0, 0.0), (double)(IMW - 1));
  double c1 = fmin(fmax(b1, 0.0), (double)(IMH - 1));
  double c2 = fmin(fmax(b2, 0.0), (double)(IMW - 1));
  double c3 = fmin(fmax(b3, 0.0), (double)(IMH - 1));
  if (tid == 0) {
    out[(n * 100 + t) * 4 + 0] = (float)c0;
    out[(n * 100 + t) * 4 + 1] = (float)c1;
    out[(n * 100 + t) * 4 + 2] = (float)c2;
    out[(n * 100 + t) * 4 + 3] = (float)c3;
    out[O_SC + n * 100 + t] = vf ? (float)sc : 0.f;
    out[O_LB + n * 100 + t] = (float)(c + 1);
    out[O_VF + n * 100 + t] = (float)vf;
  }
  if (tid < H_) Aw[tid] = wr[x2c * H_ + tid] - wr[x1c * H_ + tid];
  else if (tid < H_ + W_) { int q = tid - H_; Bw[q] = wc[y2c * W_ + q] - wc[y1c * W_ + q]; }
  __syncthreads();
  if (tid < M2_) {
    float acc = 0.f;
    if (rok && vf) {
      int rlo = i0of(x1c, H_ - 1);
      int rhi = min(i0of(x2c - 1, H_ - 1) + 1, H_ - 1);
      int qlo = i0of(y1c, W_ - 1);
      int qhi = min(i0of(y2c - 1, W_ - 1) + 1, W_ - 1);
      for (int r = rlo; r <= rhi; ++r) {
        float ar = Aw[r];
        const float* mrow = msig + ((size_t)((n * H_ + r) * W_ + qlo)) * M2_ + tid;
        float rs = 0.f;
        #pragma unroll 4
        for (int q = qlo; q <= qhi; ++q) { rs += Bw[q] * mrow[0]; mrow += M2_; }
        acc += ar * rs;
      }
      acc /= (float)area;
    }
    out[O_PB + (size_t)(n * 100 + t) * M2_ + tid] = acc;
  }
}

extern "C" void kernel_launch(void* const* d_in, const int* in_sizes, int n_in,
                              void* d_out, int out_size, void* d_ws, size_t ws_size,
                              hipStream_t stream) {
  (void)in_sizes; (void)n_in; (void)out_size; (void)ws_size;
  const float* locations = (const float*)d_in[0];
  const float* box_cls   = (const float*)d_in[1];
  const float* box_reg   = (const float*)d_in[2];
  const float* cent      = (const float*)d_in[3];
  const float* box_mask  = (const float*)d_in[4];
  float* out = (float*)d_out;

  char* ws = (char*)d_ws;
  size_t off = 0;
  auto alloc = [&](size_t bytes) -> void* {
    void* p = ws + off;
    off = (off + bytes + 255) & ~(size_t)255;
    return p;
  };
  unsigned* ghist          = (unsigned*)alloc((size_t)N_ * KB * NB * 4);
  unsigned long long* bufK = (unsigned long long*)alloc((size_t)N_ * GCAP * 8);
  unsigned* bufI           = (unsigned*)alloc((size_t)N_ * GCAP * 4);
  unsigned* cntG           = (unsigned*)alloc(16 * 4);
  unsigned* keepg          = (unsigned*)alloc((size_t)N_ * 1024 * 4);
  float* msig              = (float*)alloc((size_t)N_ * HW_ * M2_ * 4);
  float* wr                = (float*)alloc((size_t)(IMH + 1) * H_ * 4);
  float* wc                = (float*)alloc((size_t)(IMW + 1) * W_ * 4);

  k_pre<<<N_ * KB + 140 + 1, 1024, 0, stream>>>(box_cls, cent, box_mask, ghist, msig, wr, wc);
  k_compact<<<N_ * KB, 1024, 0, stream>>>(ghist, box_cls, cent, bufK, bufI, cntG, keepg);
  k_nms<<<dim3(C_, N_), 256, 0, stream>>>(bufK, bufI, cntG, locations, box_reg, keepg);
  k_finish<<<dim3(100, N_), 256, 0, stream>>>(bufK, bufI, cntG, locations, box_reg,
                                              keepg, msig, wr, wc, out);
}

// Round 12
// 91.704 us; speedup vs baseline: 1.3209x; 1.3209x over previous
//
#include <hip/hip_runtime.h>

#define DEVI __device__ __forceinline__

constexpr int N_ = 2, C_ = 80, H_ = 32, W_ = 40, HW_ = H_ * W_, HWC_ = HW_ * C_;
constexpr int KTOP = 1000, M2_ = 196;
constexpr int IMH = 256, IMW = 320;
constexpr int NB = 2048;          // f32-derived bins
constexpr int KB = 16;            // hist slices per image
constexpr int SLICE = HWC_ / KB;  // 6400 = 5*HW_
constexpr int BCAP = 2048;        // rank working-set cap (expected G ~ 1100)
constexpr int GCAP = 4096;        // global buf cap

// output layout (floats): bx[2][100][4] | sc[2][100] | lb[2][100] | prob[2][100][196] | vf[2][100]
constexpr int O_SC = 800, O_LB = 1000, O_PB = 1200, O_VF = 40400;

DEVI unsigned long long mapd(double v) {
  unsigned long long u = (unsigned long long)__double_as_longlong(v);
  return (u & 0x8000000000000000ull) ? ~u : (u | 0x8000000000000000ull);
}
DEVI double unmapd(unsigned long long k) {
  unsigned long long u = (k & 0x8000000000000000ull) ? (k ^ 0x8000000000000000ull) : ~k;
  return __longlong_as_double((long long)u);
}
DEVI int i0of(int x, int cap) {  // exact first contributing mask row/col (matches table arithmetic)
  float src = ((float)x + 0.5f) * 0.125f - 0.5f;
  src = fminf(fmaxf(src, 0.f), (float)cap);
  return (int)floorf(src);
}

// ---- K1: per-slice f32 hist | mask transpose/sigmoid | weight tables (verbatim r11) ----
__global__ __launch_bounds__(1024) void k_pre(const float* cls, const float* cent, const float* bm,
                                              unsigned* ghist, float* msig, float* wr, float* wc) {
  int b = blockIdx.x, tid = threadIdx.x;
  if (b < N_ * KB) {
    __shared__ unsigned hist[NB];
    __shared__ float ce[HW_];
    int n = b >> 4, sb = b & 15;
    size_t base = (size_t)n * HWC_ + (size_t)sb * SLICE;
    for (int j = tid; j < NB; j += 1024) hist[j] = 0;
    for (int j = tid; j < HW_; j += 1024) ce[j] = 1.f / (1.f + expf(-cent[n * HW_ + j]));
    __syncthreads();
    #pragma unroll
    for (int it = 0; it < 7; ++it) {
      int j = it * 1024 + tid;
      if (j < SLICE) {
        float aa = cls[base + j];
        float s = 1.f / (1.f + expf(-aa));
        // conservative band: f32 s <= 0.0499999 implies exact sigmoid < 0.05 (exclude safely);
        // borderline entries get the exact f64 gate downstream. (r6-r11-proven scheme)
        if (s > 0.0499999f) {
          unsigned key = __float_as_uint(s * ce[j % HW_]);   // base is a multiple of HW_
          int bin = (int)(key >> 16) - 0x3800;
          bin = bin < 0 ? 0 : (bin > NB - 1 ? NB - 1 : bin);
          atomicAdd(&hist[bin], 1u);
        }
      }
    }
    __syncthreads();
    unsigned* gh = ghist + ((size_t)n * KB + sb) * NB;
    for (int j = tid; j < NB; j += 1024) gh[j] = hist[j];
  } else if (b < N_ * KB + 140) {
    __shared__ float tile[4][32][33];
    int g = tid >> 8, sub = tid & 255;
    int tt = (b - N_ * KB) * 4 + g;             // 0..559
    int n = tt / 280, r = tt % 280, rqt = r / 7, ct = r % 7;
    int tx = sub & 31, ty = sub >> 5;           // 32x8
    int rq0 = rqt * 32, c0 = ct * 32;
    for (int i = 0; i < 4; ++i) {
      int cc = c0 + ty + i * 8, rq = rq0 + tx;
      if (cc < M2_) {
        float v = bm[((size_t)n * M2_ + cc) * HW_ + rq];
        tile[g][ty + i * 8][tx] = 1.f / (1.f + expf(-v));
      }
    }
    __syncthreads();
    for (int i = 0; i < 4; ++i) {
      int rq = rq0 + ty + i * 8, cc = c0 + tx;
      if (cc < M2_) msig[((size_t)n * HW_ + rq) * M2_ + cc] = tile[g][tx][ty + i * 8];
    }
  } else {
    int t = tid;
    if (t < H_) {
      int r = t; float acc = 0.f; wr[0 * H_ + r] = 0.f;
      for (int x = 0; x < IMH; ++x) {
        float src = ((float)x + 0.5f) * ((float)H_ / (float)IMH) - 0.5f;
        src = fminf(fmaxf(src, 0.f), (float)(H_ - 1));
        int i0 = (int)floorf(src); int i1 = min(i0 + 1, H_ - 1);
        float lam = src - (float)i0;
        float w = ((r == i0) ? (1.f - lam) : 0.f) + ((r == i1) ? lam : 0.f);
        acc += w; wr[(x + 1) * H_ + r] = acc;
      }
    } else if (t < H_ + W_) {
      int q = t - H_; float acc = 0.f; wc[0 * W_ + q] = 0.f;
      for (int y = 0; y < IMW; ++y) {
        float src = ((float)y + 0.5f) * ((float)W_ / (float)IMW) - 0.5f;
        src = fminf(fmaxf(src, 0.f), (float)(W_ - 1));
        int i0 = (int)floorf(src); int i1 = min(i0 + 1, W_ - 1);
        float lam = src - (float)i0;
        float w = ((q == i0) ? (1.f - lam) : 0.f) + ((q == i1) ? lam : 0.f);
        acc += w; wc[(y + 1) * W_ + q] = acc;
      }
    }
  }
}

// ---- K2: 32 blocks: redundant D,Dg -> slice compact -> write EXACT f64 keys + idx (verbatim r11) ----
__global__ __launch_bounds__(1024) void k_compact(const unsigned* ghist, const float* cls, const float* cent,
                                                  unsigned long long* bufK, unsigned* bufI, unsigned* cntG) {
  __shared__ unsigned wtot[16], wabove[16], sliceCnt[16], sliceOff[17];
  __shared__ unsigned sD, lcnt;
  __shared__ float ce[HW_];
  int b = blockIdx.x, n = b >> 4, sb = b & 15;
  int tid = threadIdx.x, lane = tid & 63, wid = tid >> 6;
  for (int j = tid; j < HW_; j += 1024) ce[j] = 1.f / (1.f + expf(-cent[n * HW_ + j]));
  const unsigned* gh = ghist + (size_t)n * KB * NB;
  unsigned a = 0, bv = 0;
  #pragma unroll
  for (int q = 0; q < KB; ++q) { a += gh[q * NB + 2 * tid]; bv += gh[q * NB + 2 * tid + 1]; }
  if (tid == 0) { sD = 0; lcnt = 0; }
  unsigned s2 = a + bv, suf = s2;
  for (int off = 1; off < 64; off <<= 1) {
    unsigned v = __shfl_down(suf, off);
    if (lane + off < 64) suf += v;
  }
  if (lane == 0) wtot[wid] = suf;
  __syncthreads();
  if (tid == 0) { unsigned acc = 0; for (int w = 15; w >= 0; --w) { wabove[w] = acc; acc += wtot[w]; } }
  __syncthreads();
  unsigned above = (suf - s2) + wabove[wid];
  if (above < 1000u && above + bv >= 1000u) sD = (unsigned)(2 * tid + 1);
  if (above + bv < 1000u && above + bv + a >= 1000u) sD = (unsigned)(2 * tid);
  __syncthreads();
  unsigned D = sD;
  unsigned Dg = (D > 0) ? D - 1 : 0;            // guard bin covers f32-vs-f64 straddle (r6-proven)
  {
    unsigned acc = 0;
    for (int bin = (int)Dg + lane; bin < NB; bin += 64) acc += gh[wid * NB + bin];
    for (int off = 32; off; off >>= 1) acc += __shfl_down(acc, off);
    if (lane == 0) sliceCnt[wid] = acc;
  }
  __syncthreads();
  if (tid == 0) {
    unsigned acc = 0;
    for (int q = 0; q < KB; ++q) { sliceOff[q] = acc; acc += sliceCnt[q]; }
    sliceOff[KB] = acc;
    if (sb == 0) cntG[n] = acc;
  }
  __syncthreads();
  unsigned myStart = sliceOff[sb];
  size_t gbase = (size_t)n * HWC_ + (size_t)sb * SLICE;
  for (int it = 0; it < 7; ++it) {
    int j = it * 1024 + tid;
    bool win = false; float aa = 0.f;
    if (j < SLICE) {
      aa = cls[gbase + j];
      float s = 1.f / (1.f + expf(-aa));
      if (s > 0.0499999f) {
        unsigned key = __float_as_uint(s * ce[j % HW_]);
        int bin = (int)(key >> 16) - 0x3800;
        bin = bin < 0 ? 0 : (bin > NB - 1 ? NB - 1 : bin);
        win = ((unsigned)bin >= Dg);
      }
    }
    unsigned long long mb = __ballot(win);
    if (mb) {
      int lead = __builtin_ctzll(mb);
      unsigned offw = 0;
      if (lane == lead) offw = atomicAdd(&lcnt, (unsigned)__popcll(mb));
      offw = (unsigned)__shfl((int)offw, lead);
      if (win) {
        unsigned pos = myStart + offw + (unsigned)__popcll(mb & ((1ull << lane) - 1ull));
        if (pos < (unsigned)GCAP) {
          int hw = j % HW_, c = sb * 5 + j / HW_;   // SLICE = 5*HW_
          double ss = 1.0 / (1.0 + exp(-(double)aa));
          double ced = 1.0 / (1.0 + exp(-(double)cent[n * HW_ + hw]));
          double v = (ss > 0.05) ? ss * ced : -1e9; // exact reference gate + key
          bufK[(size_t)n * GCAP + pos] = mapd(v);
          bufI[(size_t)n * GCAP + pos] = (unsigned)(hw * C_ + c);  // logical [HW,C] flat index
        }
      }
    }
  }
}

// ---- K3: per-image (2 blocks, ONCE): exact-bucket counting sort + rank -> f64 decode ----
struct RankSh {
  unsigned long long K[BCAP];
  unsigned I[BCAP];
  unsigned short eb[BCAP];
  unsigned short ord[BCAP];
  unsigned bh[NB], bs[NB], cur[NB];
  unsigned long long Ks[1024];
  unsigned Is[1024];
  unsigned wtot[16], wabove[16];
};

__global__ __launch_bounds__(1024) void k_rankdec(const unsigned long long* bufK, const unsigned* bufI,
                                                  const unsigned* cntG, const float* loc, const float* breg,
                                                  double* bxd, double* scd, int* lab, int* vld, int* rg,
                                                  unsigned* keepg) {
  __shared__ RankSh sh;
  int n = blockIdx.x, tid = threadIdx.x, lane = tid & 63, wid = tid >> 6;
  keepg[n * 1024 + tid] = 0;
  int G = (int)cntG[n]; if (G > BCAP) G = BCAP;
  for (int j = tid; j < NB; j += 1024) sh.bh[j] = 0;
  for (int p = tid; p < G; p += 1024) {
    sh.K[p] = bufK[(size_t)n * GCAP + p];
    sh.I[p] = bufI[(size_t)n * GCAP + p];
  }
  __syncthreads();
  // exact bucket from (float)(f64 key): monotone cast => bucket order bit-exact (r10-proven)
  for (int p = tid; p < G; p += 1024) {
    double v = unmapd(sh.K[p]);
    int bb = 0;
    if (v > 0.0) {
      unsigned kb = __float_as_uint((float)v);
      bb = (int)(kb >> 16) - 0x3800;
      bb = bb < 0 ? 0 : (bb > NB - 1 ? NB - 1 : bb);
    }
    sh.eb[p] = (unsigned short)bb;
    atomicAdd(&sh.bh[bb], 1u);
  }
  __syncthreads();
  // suffix scan over bucket hist (thread owns bins 2tid, 2tid+1; r10-proven snippet)
  {
    unsigned a2 = sh.bh[2 * tid], b2 = sh.bh[2 * tid + 1];
    unsigned s3 = a2 + b2, suf2 = s3;
    for (int off = 1; off < 64; off <<= 1) {
      unsigned v = __shfl_down(suf2, off);
      if (lane + off < 64) suf2 += v;
    }
    if (lane == 0) sh.wtot[wid] = suf2;
    __syncthreads();
    if (tid == 0) { unsigned acc = 0; for (int w = 15; w >= 0; --w) { sh.wabove[w] = acc; acc += sh.wtot[w]; } }
    __syncthreads();
    unsigned above2 = (suf2 - s3) + sh.wabove[wid];
    sh.bs[2 * tid + 1] = above2;  sh.cur[2 * tid + 1] = above2;
    sh.bs[2 * tid] = above2 + b2; sh.cur[2 * tid] = above2 + b2;
  }
  __syncthreads();
  for (int p = tid; p < G; p += 1024) {
    unsigned p2 = atomicAdd(&sh.cur[sh.eb[p]], 1u);
    sh.ord[p2] = (unsigned short)p;
  }
  __syncthreads();
  // exact rank within bucket (avg 1-2 mates; strict total order => permutation) -> place; pad
  for (int p = tid; p < G; p += 1024) {
    int bb = sh.eb[p];
    unsigned lo = sh.bs[bb], len = sh.bh[bb];
    unsigned long long k1 = sh.K[p]; unsigned i1 = sh.I[p];
    unsigned r = lo;
    for (unsigned q = lo; q < lo + len; ++q) {
      int j = sh.ord[q];
      unsigned long long kj = sh.K[j]; unsigned ij = sh.I[j];
      if ((kj > k1) || (kj == k1 && ij < i1)) ++r;
    }
    if (r < 1024u) { sh.Ks[r] = k1; sh.Is[r] = i1; }
  }
  for (int j = G + tid; j < 1024; j += 1024) { sh.Ks[j] = 0ull; sh.Is[j] = 0xFFFFFFFFu; }
  __syncthreads();
  // decode top-1000 (f64, exact vs np ref) -> per-candidate globals (verbatim r5)
  if (tid < KTOP) {
    unsigned long long key = sh.Ks[tid];
    unsigned idx = sh.Is[tid];
    double v = unmapd(key);
    int valid = (v > -5e8) && (idx < (unsigned)HWC_);
    if (idx >= (unsigned)HWC_) idx = 0;
    int hw = (int)(idx / C_), c = (int)(idx % C_);
    double lx = (double)loc[hw * 2 + 0], ly = (double)loc[hw * 2 + 1];
    const float* rg4 = breg + (size_t)n * 4 * HW_;
    double r0 = (double)rg4[0 * HW_ + hw], r1 = (double)rg4[1 * HW_ + hw];
    double r2 = (double)rg4[2 * HW_ + hw], r3 = (double)rg4[3 * HW_ + hw];
    double b0 = lx - r0, b1 = ly - r1, b2 = lx + r2, b3 = ly + r3;
    double sc = valid ? sqrt(v) : 0.0;
    int bi0 = (int)b0, bi1 = (int)b1, bi2 = (int)b2, bi3 = (int)b3;
    int x1 = max(bi0, 0), x2 = min(bi2, IMH - 1), y1 = max(bi1, 0), y2 = min(bi3, IMW - 1);
    int rok = (x1 < x2) && (y1 < x2) && (y1 < y2);   // ref bug replicated
    int x1c = min(max(x1, 0), IMH), x2c = min(max(x2, 0), IMH);
    int y1c = min(max(y1, 0), IMW), y2c = min(max(y2, 0), IMW);
    int area = max((x2c - x1c) * (y2c - y1c), 1);
    double c0 = fmin(fmax(b0, 0.0), (double)(IMW - 1));
    double c1 = fmin(fmax(b1, 0.0), (double)(IMH - 1));
    double c2 = fmin(fmax(b2, 0.0), (double)(IMW - 1));
    double c3 = fmin(fmax(b3, 0.0), (double)(IMH - 1));
    size_t base = (size_t)n * 1024 + tid;
    bxd[base * 4 + 0] = c0; bxd[base * 4 + 1] = c1; bxd[base * 4 + 2] = c2; bxd[base * 4 + 3] = c3;
    scd[base] = sc; lab[base] = c + 1; vld[base] = valid;
    int* r8 = rg + base * 8;
    r8[0] = x1c; r8[1] = x2c; r8[2] = y1c; r8[3] = y2c; r8[4] = area; r8[5] = rok;
  }
}

// ---- K4: per-(image,class) greedy NMS (verbatim r5) ----
__global__ void k_nms(const double* bxd, const int* lab, const int* vld, unsigned* keepg) {
  int cls = blockIdx.x + 1, n = blockIdx.y, tid = threadIdx.x; // 64 threads = 1 wave
  __shared__ int mk[KTOP];
  __shared__ double mb0[KTOP], mb1[KTOP], mb2[KTOP], mb3[KTOP], ma[KTOP];
  __shared__ unsigned char kept[KTOP];
  int m = 0;
  for (int base = 0; base < KTOP; base += 64) {
    int t = base + tid;
    bool pred = (t < KTOP) && (lab[n * 1024 + t] == cls) && (vld[n * 1024 + t] != 0);
    unsigned long long bb = __ballot(pred);
    if (pred) {
      int pos = m + (int)__popcll(bb & ((1ull << tid) - 1ull));
      mk[pos] = t;
      const double* p = bxd + ((size_t)n * 1024 + t) * 4;
      double b0 = p[0], b1 = p[1], b2 = p[2], b3 = p[3];
      mb0[pos] = b0; mb1[pos] = b1; mb2[pos] = b2; mb3[pos] = b3;
      ma[pos] = (b2 - b0 + 1.0) * (b3 - b1 + 1.0);
      kept[pos] = 1;
    }
    m += (int)__popcll(bb);
  }
  __syncthreads();
  for (int i = 0; i < m; ++i) {
    if (kept[i]) {
      double x1 = mb0[i], y1 = mb1[i], x2 = mb2[i], y2 = mb3[i], ai = ma[i];
      for (int j = i + 1 + tid; j < m; j += 64) {
        double ltx = fmax(x1, mb0[j]), lty = fmax(y1, mb1[j]);
        double rbx = fmin(x2, mb2[j]), rby = fmin(y2, mb3[j]);
        double iw = fmax(rbx - ltx + 1.0, 0.0), ih = fmax(rby - lty + 1.0, 0.0);
        double inter = iw * ih;
        double uni = ai + ma[j] - inter;
        if (inter / fmax(uni, 1e-6) > 0.6) kept[j] = 0;
      }
    }
    __syncthreads();
  }
  for (int i = tid; i < m; i += 64) keepg[n * 1024 + mk[i]] = (unsigned)kept[i];
}

// ---- K5: fused stable partition + outputs + mask prob (verbatim r5) ----
__global__ __launch_bounds__(256) void k_finish(const unsigned* keepg, const double* bxd,
                                                const double* scd, const int* lab, const int* rg,
                                                const float* msig, const float* wr, const float* wc,
                                                float* out) {
  int t = blockIdx.x, n = blockIdx.y, tid = threadIdx.x, lane = tid & 63, wid = tid >> 6;
  __shared__ int lsel[100], lvf[100];
  __shared__ unsigned woff[4]; __shared__ unsigned sS;
  __shared__ float A[H_], B[W_];

  int i0 = tid * 4;
  unsigned ff[4]; int lc = 0;
  for (int j = 0; j < 4; ++j) {
    int i = i0 + j;
    ff[j] = (i < KTOP) ? keepg[n * 1024 + i] : 0u;
    lc += (int)ff[j];
  }
  unsigned pre = (unsigned)lc;
  for (int off = 1; off < 64; off <<= 1) {
    unsigned v = __shfl_up(pre, off);
    if (lane >= off) pre += v;
  }
  if (lane == 63) woff[wid] = pre;
  __syncthreads();
  if (tid == 0) { unsigned acc = 0; for (int w = 0; w < 4; ++w) { unsigned tmp = woff[w]; woff[w] = acc; acc += tmp; } sS = acc; }
  __syncthreads();
  int kpre = (int)(woff[wid] + pre - (unsigned)lc);
  int S = (int)sS;
  for (int j = 0; j < 4; ++j) {
    int i = i0 + j;
    if (i < KTOP) {
      if (ff[j]) { if (kpre < 100) { lsel[kpre] = i; lvf[kpre] = 1; } kpre++; }
      else { int slot = S + (i - kpre); if (slot < 100) { lsel[slot] = i; lvf[slot] = 0; } }
    }
  }
  __syncthreads();

  int k = lsel[t], vf = lvf[t];
  if (tid == 0) {
    const double* bb = bxd + ((size_t)n * 1024 + k) * 4;
    out[(n * 100 + t) * 4 + 0] = (float)bb[0];
    out[(n * 100 + t) * 4 + 1] = (float)bb[1];
    out[(n * 100 + t) * 4 + 2] = (float)bb[2];
    out[(n * 100 + t) * 4 + 3] = (float)bb[3];
    out[O_SC + n * 100 + t] = vf ? (float)scd[n * 1024 + k] : 0.f;
    out[O_LB + n * 100 + t] = (float)lab[n * 1024 + k];
    out[O_VF + n * 100 + t] = (float)vf;
  }
  const int* r8 = rg + ((size_t)n * 1024 + k) * 8;
  int x1c = r8[0], x2c = r8[1], y1c = r8[2], y2c = r8[3], area = r8[4], rok = r8[5];
  if (tid < H_) A[tid] = wr[x2c * H_ + tid] - wr[x1c * H_ + tid];
  else if (tid < H_ + W_) { int q = tid - H_; B[q] = wc[y2c * W_ + q] - wc[y1c * W_ + q]; }
  __syncthreads();
  if (tid < M2_) {
    float acc = 0.f;
    if (rok && vf) {
      int rlo = i0of(x1c, H_ - 1);
      int rhi = min(i0of(x2c - 1, H_ - 1) + 1, H_ - 1);
      int qlo = i0of(y1c, W_ - 1);
      int qhi = min(i0of(y2c - 1, W_ - 1) + 1, W_ - 1);
      for (int r = rlo; r <= rhi; ++r) {
        float ar = A[r];
        const float* mrow = msig + ((size_t)((n * H_ + r) * W_ + qlo)) * M2_ + tid;
        float rs = 0.f;
        #pragma unroll 4
        for (int q = qlo; q <= qhi; ++q) { rs += B[q] * mrow[0]; mrow += M2_; }
        acc += ar * rs;
      }
      acc /= (float)area;
    }
    out[O_PB + (size_t)(n * 100 + t) * M2_ + tid] = acc;
  }
}

extern "C" void kernel_launch(void* const* d_in, const int* in_sizes, int n_in,
                              void* d_out, int out_size, void* d_ws, size_t ws_size,
                              hipStream_t stream) {
  (void)in_sizes; (void)n_in; (void)out_size; (void)ws_size;
  const float* locations = (const float*)d_in[0];
  const float* box_cls   = (const float*)d_in[1];
  const float* box_reg   = (const float*)d_in[2];
  const float* cent      = (const float*)d_in[3];
  const float* box_mask  = (const float*)d_in[4];
  float* out = (float*)d_out;

  char* ws = (char*)d_ws;
  size_t off = 0;
  auto alloc = [&](size_t bytes) -> void* {
    void* p = ws + off;
    off = (off + bytes + 255) & ~(size_t)255;
    return p;
  };
  unsigned* ghist          = (unsigned*)alloc((size_t)N_ * KB * NB * 4);
  unsigned long long* bufK = (unsigned long long*)alloc((size_t)N_ * GCAP * 8);
  unsigned* bufI           = (unsigned*)alloc((size_t)N_ * GCAP * 4);
  unsigned* cntG           = (unsigned*)alloc(16 * 4);
  double* bxd              = (double*)alloc((size_t)N_ * 1024 * 4 * 8);
  double* scd              = (double*)alloc((size_t)N_ * 1024 * 8);
  int* lab                 = (int*)alloc((size_t)N_ * 1024 * 4);
  int* vld                 = (int*)alloc((size_t)N_ * 1024 * 4);
  int* rg                  = (int*)alloc((size_t)N_ * 1024 * 8 * 4);
  unsigned* keepg          = (unsigned*)alloc((size_t)N_ * 1024 * 4);
  float* msig              = (float*)alloc((size_t)N_ * HW_ * M2_ * 4);
  float* wr                = (float*)alloc((size_t)(IMH + 1) * H_ * 4);
  float* wc                = (float*)alloc((size_t)(IMW + 1) * W_ * 4);

  k_pre<<<N_ * KB + 140 + 1, 1024, 0, stream>>>(box_cls, cent, box_mask, ghist, msig, wr, wc);
  k_compact<<<N_ * KB, 1024, 0, stream>>>(ghist, box_cls, cent, bufK, bufI, cntG);
  k_rankdec<<<N_, 1024, 0, stream>>>(bufK, bufI, cntG, locations, box_reg,
                                     bxd, scd, lab, vld, rg, keepg);
  k_nms<<<dim3(C_, N_), 64, 0, stream>>>(bxd, lab, vld, keepg);
  k_finish<<<dim3(100, N_), 256, 0, stream>>>(keepg, bxd, scd, lab, rg, msig, wr, wc, out);
}